// Round 23
// baseline (97.999 us; speedup 1.0000x reference)
//
#include <hip/hip_runtime.h>
#include <stdint.h>

#define S_GRID 7
#define INV_S  0.14285714285714285f   // 1/7, rel err ~6e-8 (tolerance is 0.89 abs)
#define N_CH 30
#define MAXB 8192          // max compacted boxes (actual data: 6272)
#define NTILE 32           // j-tiles (256 cols each)
#define NCHUNK 80          // i-chunks (R18 config)
#define CHUNK_MAX 104      // ceil(MAXB/NCHUNK) aligned up
#define REPEAT 4           // DIAGNOSTIC: x4 passes, bit-identical (strict-> argmax idempotent).
                           // Separates staging S from loop L: row = S+4L; total = base+3L.

// ---- ws layout (bytes) ----
// 0      : float acc[4] {xy+wh, obj, nobj, class}
// 16     : int ctr        (obj-cell allocator)
// 20     : int finalCtr
// 1024   : u64 maxkey[MAXB]   (65536)  -> 66560
// 66560  : float4 PB4[MAXB]   (131072) -> 197632   {x0,y0,x1,y1}
// 197632 : float4 BT4[MAXB]   (131072) -> 328704
// 328704 : float  ConfP[MAXB] (32768)  -> 361472

__global__ void k_init(float* __restrict__ acc, int* __restrict__ ctr, int* __restrict__ finalCtr) {
    if (threadIdx.x < 4)  acc[threadIdx.x] = 0.0f;
    if (threadIdx.x == 4) *ctr = 0;
    if (threadIdx.x == 5) *finalCtr = 0;
}

// one pass over P,T (R18 verbatim): unordered compaction + masked losses + maxkey zeroing
__global__ void k_prep(const float* __restrict__ P, const float* __restrict__ T, int ncell,
                       int* __restrict__ ctr,
                       float4* __restrict__ PB4, float4* __restrict__ BT4,
                       float* __restrict__ ConfP,
                       float* __restrict__ acc,
                       unsigned long long* __restrict__ maxkey) {
    int gid = blockIdx.x * 256 + threadIdx.x;
    if (gid < MAXB) maxkey[gid] = 0ull;      // plain store; visible to k_match at boundary

    int cell = gid;
    float2 pr[15], tr[15];
    if (cell < ncell) {
        const float2* p2 = (const float2*)(P + (size_t)cell * N_CH);
        const float2* t2 = (const float2*)(T + (size_t)cell * N_CH);
        #pragma unroll
        for (int k = 0; k < 15; ++k) { pr[k] = p2[k]; tr[k] = t2[k]; }
    } else {
        #pragma unroll
        for (int k = 0; k < 15; ++k) { pr[k] = make_float2(0.f, 0.f); tr[k] = make_float2(0.f, 0.f); }
    }
    bool obj = (cell < ncell) && (tr[2].x == 1.0f);   // t[4]

    int lane = threadIdx.x & 63;
    unsigned long long bm = __ballot(obj);
    int wcnt = __popcll(bm);
    int base = 0;
    if (lane == 0 && wcnt) base = atomicAdd(ctr, wcnt);
    base = __shfl(base, 0);

    float cls = 0.f, nob = 0.f;
    if (cell < ncell) {
        if (obj) {
            #pragma unroll
            for (int k = 5; k < 15; ++k) {            // floats 10..29
                float d0 = pr[k].x - tr[k].x, d1 = pr[k].y - tr[k].y;
                cls += d0 * d0 + d1 * d1;
            }
        } else {
            float d0 = pr[2].x - tr[2].x;             // p[4]-t[4]
            float d1 = pr[4].y - tr[4].y;             // p[9]-t[9]
            nob = d0 * d0 + d1 * d1;
        }
    }
    #pragma unroll
    for (int o = 32; o; o >>= 1) { cls += __shfl_down(cls, o); nob += __shfl_down(nob, o); }
    if (lane == 0) {
        if (cls != 0.f) atomicAdd(&acc[3], cls);
        if (nob != 0.f) atomicAdd(&acc[2], nob);
    }

    if (obj) {
        int rank = base + __popcll(bm & ((1ull << lane) - 1ull));
        float bx[2][5] = {
            { pr[0].x, pr[0].y, pr[1].x, pr[1].y, pr[2].x },
            { pr[2].y, pr[3].x, pr[3].y, pr[4].x, pr[4].y }
        };
        float tx[2][4] = {
            { tr[0].x, tr[0].y, tr[1].x, tr[1].y },
            { tr[2].y, tr[3].x, tr[3].y, tr[4].x }
        };
        #pragma unroll
        for (int bb = 0; bb < 2; ++bb) {
            int m = 2 * rank + bb;
            if (m < MAXB) {
                float cx = bx[bb][0] * INV_S, cy = bx[bb][1] * INV_S;
                float w = bx[bb][2], h = bx[bb][3];
                PB4[m] = make_float4(cx - 0.5f * w, cy - 0.5f * h, cx + 0.5f * w, cy + 0.5f * h);
                ConfP[m] = bx[bb][4];
                cx = tx[bb][0] * INV_S; cy = tx[bb][1] * INV_S;
                w = tx[bb][2]; h = tx[bb][3];
                BT4[m] = make_float4(cx - 0.5f * w, cy - 0.5f * h, cx + 0.5f * w, cy + 0.5f * h);
            }
        }
    }
}

// j-per-LANE match: R18's asm loop, wrapped in REPEAT for the S/L decomposition.
__global__ __launch_bounds__(256, 8)
void k_match(const float4* __restrict__ PB4, const float4* __restrict__ BT4,
             const int* __restrict__ ctr,
             unsigned long long* __restrict__ maxkey) {
    __shared__ float4 sh[CHUNK_MAX];
    __shared__ float  sa[CHUNK_MAX];
    int nb = 2 * (*ctr); if (nb > MAXB) nb = MAXB;
    int tid = threadIdx.x;
    int j = blockIdx.x * 256 + tid;
    if (blockIdx.x * 256 >= nb) return;      // whole tile beyond nb
    int c = blockIdx.y;
    int chunkLen = (((nb + NCHUNK - 1) / NCHUNK) + 7) & ~7;   // multiple of 8
    int i0 = c * chunkLen;
    int i1 = min(nb, i0 + chunkLen);
    if (i0 >= i1) return;

    int len = i1 - i0;
    int padded = (len + 7) & ~7;
    if (tid < padded) {                       // padded <= 104 < 256: single pass
        float4 v = (tid < len) ? PB4[i0 + tid] : make_float4(3.f, 3.f, 3.f, 3.f);
        sh[tid] = v;
        sa[tid] = (v.z - v.x) * (v.w - v.y);  // pad area = 0 -> never wins once bI>=0
    }
    __syncthreads();

    float4 tb = BT4[min(j, nb - 1)];          // per-lane target box (coalesced)
    float ta = (tb.z - tb.x) * (tb.w - tb.y);
    float bI = -1.f, bS = 1.f;                // first real box always wins
    int bidx = i0;

    for (int rep = 0; rep < REPEAT; ++rep) {
        for (int kb = 0; kb < padded; kb += 8) {
            #define STEP(kk)  {                                                          \
                float4 bb = sh[kb + kk];                                                 \
                float aa = sa[kb + kk];                                                  \
                int sidx = i0 + kb + kk;                                                 \
                float t0, t1, t2, t3;                                                    \
                asm("v_max_f32 %0, %7, %11\n\t"   /* lx                               */ \
                    "v_min_f32 %1, %9, %13\n\t"   /* rx                               */ \
                    "v_sub_f32 %1, %1, %0\n\t"                                           \
                    "v_max_f32 %1, 0, %1\n\t"     /* wx  (literal in src0)            */ \
                    "v_max_f32 %0, %8, %12\n\t"   /* ly                               */ \
                    "v_min_f32 %2, %10, %14\n\t"  /* ry                               */ \
                    "v_sub_f32 %2, %2, %0\n\t"                                           \
                    "v_max_f32 %2, 0, %2\n\t"     /* wy                               */ \
                    "v_mul_f32 %1, %1, %2\n\t"    /* inter                            */ \
                    "v_add_f32 %0, %15, %16\n\t"  /* sum = ta + area                  */ \
                    "v_mul_f32 %2, %1, %4\n\t"    /* inter*bS                         */ \
                    "v_mul_f32 %3, %5, %0\n\t"    /* bI*sum                           */ \
                    "v_cmp_ngt_f32 vcc, %2, %3\n\t" /* vcc = !win                     */ \
                    "v_cndmask_b32 %5, %1, %5, vcc\n\t" /* bI  = win ? inter : bI     */ \
                    "v_cndmask_b32 %4, %0, %4, vcc\n\t" /* bS  = win ? sum   : bS     */ \
                    "v_cndmask_b32 %6, %17, %6, vcc"    /* bidx= win ? sidx  : bidx   */ \
                    : "=&v"(t0), "=&v"(t1), "=&v"(t2), "=&v"(t3),                        \
                      "+v"(bS), "+v"(bI), "+v"(bidx)                                     \
                    : "v"(tb.x), "v"(tb.y), "v"(tb.z), "v"(tb.w),                        \
                      "v"(bb.x), "v"(bb.y), "v"(bb.z), "v"(bb.w),                        \
                      "v"(ta), "v"(aa), "v"(sidx)                                        \
                    : "vcc");                                                            \
            }
            STEP(0) STEP(1) STEP(2) STEP(3) STEP(4) STEP(5) STEP(6) STEP(7)
            #undef STEP
        }
    }

    if (j < nb) {
        float iou = (bI >= 0.f) ? (bI / (bS - bI)) : 0.f;   // one precise divide
        unsigned long long key =
            ((unsigned long long)__float_as_uint(iou) << 32) |
            (unsigned long long)(0xFFFFFFFFu - (unsigned)bidx);
        atomicMax(&maxkey[j], key);          // bigger iou wins; ties -> smaller idx
    }
}

// final (R18 verbatim): read per-j winner, losses, reduce, 32-block ACQ_REL election.
// Reference gathers BOTH boxes by the argmax index: BPg=BP[idx], BTg=BT[idx].
__global__ void k_final(const float4* __restrict__ PB4, const float4* __restrict__ BT4,
                        const float* __restrict__ ConfP,
                        const int* __restrict__ ctr,
                        const unsigned long long* __restrict__ maxkey,
                        float* __restrict__ acc, int* __restrict__ finalCtr,
                        float* __restrict__ out, float inv_batch) {
    int nb = 2 * (*ctr); if (nb > MAXB) nb = MAXB;
    int tid = threadIdx.x;
    int j = blockIdx.x * 256 + tid;
    float sxywh = 0.f, sobj = 0.f;
    if (j < nb) {
        unsigned long long key = maxkey[j];
        float iou = __uint_as_float((unsigned)(key >> 32));
        unsigned idx = 0xFFFFFFFFu - (unsigned)(key & 0xFFFFFFFFull);
        float4 bp = PB4[idx];
        float4 bt = BT4[idx];                // by idx, matching the reference
        float cp = ConfP[idx];
        float dx = bp.x - bt.x, dy = bp.y - bt.y;
        float dw = sqrtf(bp.z) - sqrtf(bt.z);
        float dh = sqrtf(bp.w) - sqrtf(bt.w);
        sxywh = dx * dx + dy * dy + dw * dw + dh * dh;
        float dob = cp - iou;
        sobj = dob * dob;
    }
    #pragma unroll
    for (int o = 32; o; o >>= 1) { sxywh += __shfl_down(sxywh, o); sobj += __shfl_down(sobj, o); }
    if ((tid & 63) == 0) {
        if (sxywh != 0.f) atomicAdd(&acc[0], sxywh);
        if (sobj != 0.f)  atomicAdd(&acc[1], sobj);
    }
    __syncthreads();                         // drains wave-leader atomics
    if (tid == 0) {
        int old = __hip_atomic_fetch_add(finalCtr, 1, __ATOMIC_ACQ_REL, __HIP_MEMORY_SCOPE_AGENT);
        if (old == NTILE - 1) {              // last block: all adds visible
            float a0 = __hip_atomic_load(&acc[0], __ATOMIC_RELAXED, __HIP_MEMORY_SCOPE_AGENT);
            float a1 = __hip_atomic_load(&acc[1], __ATOMIC_RELAXED, __HIP_MEMORY_SCOPE_AGENT);
            float a2 = __hip_atomic_load(&acc[2], __ATOMIC_RELAXED, __HIP_MEMORY_SCOPE_AGENT);
            float a3 = __hip_atomic_load(&acc[3], __ATOMIC_RELAXED, __HIP_MEMORY_SCOPE_AGENT);
            out[0] = (5.0f * a0 + 0.5f * a2 + a1 + a3) * inv_batch;
        }
    }
}

extern "C" void kernel_launch(void* const* d_in, const int* in_sizes, int n_in,
                              void* d_out, int out_size, void* d_ws, size_t ws_size,
                              hipStream_t stream) {
    const float* P = (const float*)d_in[0];
    const float* T = (const float*)d_in[1];
    int ncell = in_sizes[0] / N_CH;                 // 25088
    int batch = ncell / (S_GRID * S_GRID);          // 512

    char* ws = (char*)d_ws;
    float* acc      = (float*)ws;
    int*   ctr      = (int*)(ws + 16);
    int*   finalCtr = (int*)(ws + 20);
    unsigned long long* maxkey = (unsigned long long*)(ws + 1024);
    float4* PB4  = (float4*)(ws + 66560);
    float4* BT4  = (float4*)(ws + 197632);
    float*  ConfP = (float*)(ws + 328704);

    int nblk = (ncell + 255) / 256;                 // 98
    k_init <<<1, 64, 0, stream>>>(acc, ctr, finalCtr);
    k_prep <<<nblk, 256, 0, stream>>>(P, T, ncell, ctr, PB4, BT4, ConfP, acc, maxkey);
    dim3 g3(NTILE, NCHUNK);                         // (32, 80); inactive blocks exit
    k_match<<<g3, 256, 0, stream>>>(PB4, BT4, ctr, maxkey);
    k_final<<<NTILE, 256, 0, stream>>>(PB4, BT4, ConfP, ctr, maxkey, acc, finalCtr,
                                       (float*)d_out, 1.0f / (float)batch);
}

// Round 24
// 51.001 us; speedup vs baseline: 1.9215x; 1.9215x over previous
//
#include <hip/hip_runtime.h>
#include <stdint.h>

#define S_GRID 7
#define INV_S  0.14285714285714285f   // 1/7, rel err ~6e-8 (tolerance is 0.89 abs)
#define N_CH 30
#define MAXB 8192          // max compacted boxes (actual data: 6272)
#define NTILE 32           // j-tiles (256 cols each)
#define NCHUNK 80          // i-chunks (R18 config, best at 51.1us)
#define CHUNK_MAX 104      // ceil(MAXB/NCHUNK) aligned up

// ---- ws layout (bytes) ----
// 0      : float acc[4] {xy+wh, obj, nobj, class}
// 16     : int ctr        (obj-cell allocator)
// 20     : int finalCtr
// 1024   : u64 maxkey[MAXB]   (65536)  -> 66560
// 66560  : float4 PB4[MAXB]   (131072) -> 197632   {x0,y0,x1,y1}
// 197632 : float4 BT4[MAXB]   (131072) -> 328704
// 328704 : float  ConfP[MAXB] (32768)  -> 361472

__global__ void k_init(float* __restrict__ acc, int* __restrict__ ctr, int* __restrict__ finalCtr) {
    if (threadIdx.x < 4)  acc[threadIdx.x] = 0.0f;
    if (threadIdx.x == 4) *ctr = 0;
    if (threadIdx.x == 5) *finalCtr = 0;
}

// one pass over P,T (R18 verbatim): unordered compaction + masked losses + maxkey zeroing
__global__ void k_prep(const float* __restrict__ P, const float* __restrict__ T, int ncell,
                       int* __restrict__ ctr,
                       float4* __restrict__ PB4, float4* __restrict__ BT4,
                       float* __restrict__ ConfP,
                       float* __restrict__ acc,
                       unsigned long long* __restrict__ maxkey) {
    int gid = blockIdx.x * 256 + threadIdx.x;
    if (gid < MAXB) maxkey[gid] = 0ull;      // plain store; visible to k_match at boundary

    int cell = gid;
    float2 pr[15], tr[15];
    if (cell < ncell) {
        const float2* p2 = (const float2*)(P + (size_t)cell * N_CH);
        const float2* t2 = (const float2*)(T + (size_t)cell * N_CH);
        #pragma unroll
        for (int k = 0; k < 15; ++k) { pr[k] = p2[k]; tr[k] = t2[k]; }
    } else {
        #pragma unroll
        for (int k = 0; k < 15; ++k) { pr[k] = make_float2(0.f, 0.f); tr[k] = make_float2(0.f, 0.f); }
    }
    bool obj = (cell < ncell) && (tr[2].x == 1.0f);   // t[4]

    int lane = threadIdx.x & 63;
    unsigned long long bm = __ballot(obj);
    int wcnt = __popcll(bm);
    int base = 0;
    if (lane == 0 && wcnt) base = atomicAdd(ctr, wcnt);
    base = __shfl(base, 0);

    float cls = 0.f, nob = 0.f;
    if (cell < ncell) {
        if (obj) {
            #pragma unroll
            for (int k = 5; k < 15; ++k) {            // floats 10..29
                float d0 = pr[k].x - tr[k].x, d1 = pr[k].y - tr[k].y;
                cls += d0 * d0 + d1 * d1;
            }
        } else {
            float d0 = pr[2].x - tr[2].x;             // p[4]-t[4]
            float d1 = pr[4].y - tr[4].y;             // p[9]-t[9]
            nob = d0 * d0 + d1 * d1;
        }
    }
    #pragma unroll
    for (int o = 32; o; o >>= 1) { cls += __shfl_down(cls, o); nob += __shfl_down(nob, o); }
    if (lane == 0) {
        if (cls != 0.f) atomicAdd(&acc[3], cls);
        if (nob != 0.f) atomicAdd(&acc[2], nob);
    }

    if (obj) {
        int rank = base + __popcll(bm & ((1ull << lane) - 1ull));
        float bx[2][5] = {
            { pr[0].x, pr[0].y, pr[1].x, pr[1].y, pr[2].x },
            { pr[2].y, pr[3].x, pr[3].y, pr[4].x, pr[4].y }
        };
        float tx[2][4] = {
            { tr[0].x, tr[0].y, tr[1].x, tr[1].y },
            { tr[2].y, tr[3].x, tr[3].y, tr[4].x }
        };
        #pragma unroll
        for (int bb = 0; bb < 2; ++bb) {
            int m = 2 * rank + bb;
            if (m < MAXB) {
                float cx = bx[bb][0] * INV_S, cy = bx[bb][1] * INV_S;
                float w = bx[bb][2], h = bx[bb][3];
                PB4[m] = make_float4(cx - 0.5f * w, cy - 0.5f * h, cx + 0.5f * w, cy + 0.5f * h);
                ConfP[m] = bx[bb][4];
                cx = tx[bb][0] * INV_S; cy = tx[bb][1] * INV_S;
                w = tx[bb][2]; h = tx[bb][3];
                BT4[m] = make_float4(cx - 0.5f * w, cy - 0.5f * h, cx + 0.5f * w, cy + 0.5f * h);
            }
        }
    }
}

// j-per-LANE match (R18 asm loop verbatim, REPEAT removed) + monotonic publish filter:
// maxkey[j] only grows, so if a relaxed load already shows >= our key, the RMW is
// provably redundant (stale-low reads just cause a harmless extra atomic).
__global__ __launch_bounds__(256, 8)
void k_match(const float4* __restrict__ PB4, const float4* __restrict__ BT4,
             const int* __restrict__ ctr,
             unsigned long long* __restrict__ maxkey) {
    __shared__ float4 sh[CHUNK_MAX];
    __shared__ float  sa[CHUNK_MAX];
    int nb = 2 * (*ctr); if (nb > MAXB) nb = MAXB;
    int tid = threadIdx.x;
    int j = blockIdx.x * 256 + tid;
    if (blockIdx.x * 256 >= nb) return;      // whole tile beyond nb
    int c = blockIdx.y;
    int chunkLen = (((nb + NCHUNK - 1) / NCHUNK) + 7) & ~7;   // multiple of 8
    int i0 = c * chunkLen;
    int i1 = min(nb, i0 + chunkLen);
    if (i0 >= i1) return;

    int len = i1 - i0;
    int padded = (len + 7) & ~7;
    if (tid < padded) {                       // padded <= 104 < 256: single pass
        float4 v = (tid < len) ? PB4[i0 + tid] : make_float4(3.f, 3.f, 3.f, 3.f);
        sh[tid] = v;
        sa[tid] = (v.z - v.x) * (v.w - v.y);  // pad area = 0 -> never wins once bI>=0
    }
    __syncthreads();

    float4 tb = BT4[min(j, nb - 1)];          // per-lane target box (coalesced)
    float ta = (tb.z - tb.x) * (tb.w - tb.y);
    float bI = -1.f, bS = 1.f;                // first real box always wins
    int bidx = i0;

    for (int kb = 0; kb < padded; kb += 8) {
        #define STEP(kk)  {                                                          \
            float4 bb = sh[kb + kk];                                                 \
            float aa = sa[kb + kk];                                                  \
            int sidx = i0 + kb + kk;                                                 \
            float t0, t1, t2, t3;                                                    \
            asm("v_max_f32 %0, %7, %11\n\t"   /* lx                               */ \
                "v_min_f32 %1, %9, %13\n\t"   /* rx                               */ \
                "v_sub_f32 %1, %1, %0\n\t"                                           \
                "v_max_f32 %1, 0, %1\n\t"     /* wx  (literal in src0)            */ \
                "v_max_f32 %0, %8, %12\n\t"   /* ly                               */ \
                "v_min_f32 %2, %10, %14\n\t"  /* ry                               */ \
                "v_sub_f32 %2, %2, %0\n\t"                                           \
                "v_max_f32 %2, 0, %2\n\t"     /* wy                               */ \
                "v_mul_f32 %1, %1, %2\n\t"    /* inter                            */ \
                "v_add_f32 %0, %15, %16\n\t"  /* sum = ta + area                  */ \
                "v_mul_f32 %2, %1, %4\n\t"    /* inter*bS                         */ \
                "v_mul_f32 %3, %5, %0\n\t"    /* bI*sum                           */ \
                "v_cmp_ngt_f32 vcc, %2, %3\n\t" /* vcc = !win                     */ \
                "v_cndmask_b32 %5, %1, %5, vcc\n\t" /* bI  = win ? inter : bI     */ \
                "v_cndmask_b32 %4, %0, %4, vcc\n\t" /* bS  = win ? sum   : bS     */ \
                "v_cndmask_b32 %6, %17, %6, vcc"    /* bidx= win ? sidx  : bidx   */ \
                : "=&v"(t0), "=&v"(t1), "=&v"(t2), "=&v"(t3),                        \
                  "+v"(bS), "+v"(bI), "+v"(bidx)                                     \
                : "v"(tb.x), "v"(tb.y), "v"(tb.z), "v"(tb.w),                        \
                  "v"(bb.x), "v"(bb.y), "v"(bb.z), "v"(bb.w),                        \
                  "v"(ta), "v"(aa), "v"(sidx)                                        \
                : "vcc");                                                            \
        }
        STEP(0) STEP(1) STEP(2) STEP(3) STEP(4) STEP(5) STEP(6) STEP(7)
        #undef STEP
    }

    if (j < nb) {
        float iou = (bI >= 0.f) ? (bI / (bS - bI)) : 0.f;   // one precise divide
        unsigned long long key =
            ((unsigned long long)__float_as_uint(iou) << 32) |
            (unsigned long long)(0xFFFFFFFFu - (unsigned)bidx);
        // monotonic filter: skip the far-RMW when provably redundant
        unsigned long long cur = __hip_atomic_load(&maxkey[j], __ATOMIC_RELAXED,
                                                   __HIP_MEMORY_SCOPE_AGENT);
        if (key > cur)
            atomicMax(&maxkey[j], key);      // bigger iou wins; ties -> smaller idx
    }
}

// final (R18 verbatim): read per-j winner, losses, reduce, 32-block ACQ_REL election.
// Reference gathers BOTH boxes by the argmax index: BPg=BP[idx], BTg=BT[idx].
__global__ void k_final(const float4* __restrict__ PB4, const float4* __restrict__ BT4,
                        const float* __restrict__ ConfP,
                        const int* __restrict__ ctr,
                        const unsigned long long* __restrict__ maxkey,
                        float* __restrict__ acc, int* __restrict__ finalCtr,
                        float* __restrict__ out, float inv_batch) {
    int nb = 2 * (*ctr); if (nb > MAXB) nb = MAXB;
    int tid = threadIdx.x;
    int j = blockIdx.x * 256 + tid;
    float sxywh = 0.f, sobj = 0.f;
    if (j < nb) {
        unsigned long long key = maxkey[j];
        float iou = __uint_as_float((unsigned)(key >> 32));
        unsigned idx = 0xFFFFFFFFu - (unsigned)(key & 0xFFFFFFFFull);
        float4 bp = PB4[idx];
        float4 bt = BT4[idx];                // by idx, matching the reference
        float cp = ConfP[idx];
        float dx = bp.x - bt.x, dy = bp.y - bt.y;
        float dw = sqrtf(bp.z) - sqrtf(bt.z);
        float dh = sqrtf(bp.w) - sqrtf(bt.w);
        sxywh = dx * dx + dy * dy + dw * dw + dh * dh;
        float dob = cp - iou;
        sobj = dob * dob;
    }
    #pragma unroll
    for (int o = 32; o; o >>= 1) { sxywh += __shfl_down(sxywh, o); sobj += __shfl_down(sobj, o); }
    if ((tid & 63) == 0) {
        if (sxywh != 0.f) atomicAdd(&acc[0], sxywh);
        if (sobj != 0.f)  atomicAdd(&acc[1], sobj);
    }
    __syncthreads();                         // drains wave-leader atomics
    if (tid == 0) {
        int old = __hip_atomic_fetch_add(finalCtr, 1, __ATOMIC_ACQ_REL, __HIP_MEMORY_SCOPE_AGENT);
        if (old == NTILE - 1) {              // last block: all adds visible
            float a0 = __hip_atomic_load(&acc[0], __ATOMIC_RELAXED, __HIP_MEMORY_SCOPE_AGENT);
            float a1 = __hip_atomic_load(&acc[1], __ATOMIC_RELAXED, __HIP_MEMORY_SCOPE_AGENT);
            float a2 = __hip_atomic_load(&acc[2], __ATOMIC_RELAXED, __HIP_MEMORY_SCOPE_AGENT);
            float a3 = __hip_atomic_load(&acc[3], __ATOMIC_RELAXED, __HIP_MEMORY_SCOPE_AGENT);
            out[0] = (5.0f * a0 + 0.5f * a2 + a1 + a3) * inv_batch;
        }
    }
}

extern "C" void kernel_launch(void* const* d_in, const int* in_sizes, int n_in,
                              void* d_out, int out_size, void* d_ws, size_t ws_size,
                              hipStream_t stream) {
    const float* P = (const float*)d_in[0];
    const float* T = (const float*)d_in[1];
    int ncell = in_sizes[0] / N_CH;                 // 25088
    int batch = ncell / (S_GRID * S_GRID);          // 512

    char* ws = (char*)d_ws;
    float* acc      = (float*)ws;
    int*   ctr      = (int*)(ws + 16);
    int*   finalCtr = (int*)(ws + 20);
    unsigned long long* maxkey = (unsigned long long*)(ws + 1024);
    float4* PB4  = (float4*)(ws + 66560);
    float4* BT4  = (float4*)(ws + 197632);
    float*  ConfP = (float*)(ws + 328704);

    int nblk = (ncell + 255) / 256;                 // 98
    k_init <<<1, 64, 0, stream>>>(acc, ctr, finalCtr);
    k_prep <<<nblk, 256, 0, stream>>>(P, T, ncell, ctr, PB4, BT4, ConfP, acc, maxkey);
    dim3 g3(NTILE, NCHUNK);                         // (32, 80); inactive blocks exit
    k_match<<<g3, 256, 0, stream>>>(PB4, BT4, ctr, maxkey);
    k_final<<<NTILE, 256, 0, stream>>>(PB4, BT4, ConfP, ctr, maxkey, acc, finalCtr,
                                       (float*)d_out, 1.0f / (float)batch);
}